// Round 7
// baseline (377.585 us; speedup 1.0000x reference)
//
#include <hip/hip_runtime.h>

// Problem constants
#define BB 4
#define LL 2048
#define DD 1024
#define NH 16
#define DH 64
#define MM (BB*LL)   // 8192 rows

typedef _Float16 half8 __attribute__((ext_vector_type(8)));
typedef _Float16 half4 __attribute__((ext_vector_type(4)));
typedef _Float16 half2 __attribute__((ext_vector_type(2)));
typedef float floatx4 __attribute__((ext_vector_type(4)));
typedef float floatx16 __attribute__((ext_vector_type(16)));
typedef unsigned uint4v __attribute__((ext_vector_type(4)));

__device__ __forceinline__ void gload_lds16(const void* g, void* l) {
    __builtin_amdgcn_global_load_lds((const __attribute__((address_space(1))) void*)g,
                                     (__attribute__((address_space(3))) void*)l,
                                     16, 0, 0);
}

__device__ __forceinline__ floatx4 mfma16(half8 a, half8 b, floatx4 c) {
    return __builtin_amdgcn_mfma_f32_16x16x32_f16(a, b, c, 0, 0, 0);
}

__device__ __forceinline__ floatx16 mfma32(half8 a, half8 b, floatx16 c) {
    return __builtin_amdgcn_mfma_f32_32x32x16_f16(a, b, c, 0, 0, 0);
}

__device__ __forceinline__ unsigned pkh(float a, float b) {
    return __builtin_bit_cast(unsigned, __builtin_amdgcn_cvt_pkrtz(a, b));
}

// ---------------- fused fp32 -> fp16 convert (all 7 tensors, 1 launch) ----------------
__global__ __launch_bounds__(256) void cvt_all(const float* __restrict__ q,
                                               const float* __restrict__ k,
                                               const float* __restrict__ v,
                                               const float* __restrict__ Wq,
                                               const float* __restrict__ Wk,
                                               const float* __restrict__ Wv,
                                               const float* __restrict__ Wo,
                                               _Float16* __restrict__ dst) {
    const int BIG = 8192;    // blocks per big tensor (8.39M elems / 1024)
    const int SML = 1024;    // blocks per weight tensor
    const size_t NQKV = (size_t)MM * DD;
    const size_t NW = (size_t)DD * DD;
    int b = blockIdx.x;
    const float* src;
    size_t off;
    int lb;
    if (b < 3 * BIG) {
        int t = b / BIG;
        src = t == 0 ? q : (t == 1 ? k : v);
        off = (size_t)t * NQKV;
        lb = b - t * BIG;
    } else {
        int t = (b - 3 * BIG) / SML;
        src = t == 0 ? Wq : (t == 1 ? Wk : (t == 2 ? Wv : Wo));
        off = 3 * NQKV + (size_t)t * NW;
        lb = b - 3 * BIG - t * SML;
    }
    size_t i = (size_t)lb * 256 + threadIdx.x;
    float4 f = ((const float4*)src)[i];
    half4 h;
    h[0] = (_Float16)f.x; h[1] = (_Float16)f.y;
    h[2] = (_Float16)f.z; h[3] = (_Float16)f.w;
    ((half4*)(dst + off))[i] = h;
}

// ---------------- fused QKV projection GEMM (2-phase double-buffered) ----------------
__global__ __launch_bounds__(256) void gemm_qkv(const _Float16* __restrict__ qkv16,
                                                const _Float16* __restrict__ wq,
                                                const _Float16* __restrict__ wk,
                                                const _Float16* __restrict__ wv,
                                                const float* __restrict__ bq,
                                                const float* __restrict__ bk,
                                                const float* __restrict__ bv,
                                                _Float16* __restrict__ Qp,
                                                _Float16* __restrict__ Kp,
                                                _Float16* __restrict__ VtG) {
    const int K = 1024;
    __shared__ _Float16 As[2][128 * 32];
    __shared__ _Float16 Bs[2][128 * 32];

    int tid = threadIdx.x;
    int wave = tid >> 6, lane = tid & 63;
    int quad = lane >> 4, l15 = lane & 15;
    int wrow = (wave >> 1) * 64, wcol = (wave & 1) * 64;
    int bx = blockIdx.x;
    int which = bx >> 3;  // 0=Q, 1=K, 2=V
    int m0 = blockIdx.y * 128;
    int n0 = (bx & 7) * 128;

    const _Float16* A = qkv16 + (size_t)which * ((size_t)MM * DD);
    const _Float16* W = which == 0 ? wq : (which == 1 ? wk : wv);
    const float* bias = which == 0 ? bq : (which == 1 ? bk : bv);

    floatx4 acc[4][4] = {};

    int srow = tid >> 2, sseg = tid & 3;
    const _Float16* Ag0 = A + (size_t)(m0 + srow) * K + sseg * 8;
    const _Float16* Ag1 = Ag0 + (size_t)64 * K;
    const _Float16* Bg0 = W + (size_t)(n0 + srow) * K + sseg * 8;
    const _Float16* Bg1 = Bg0 + (size_t)64 * K;
    int lo0 = tid * 16, lo1 = (256 + tid) * 16;

    gload_lds16(Ag0, (char*)As[0] + lo0);
    gload_lds16(Ag1, (char*)As[0] + lo1);
    gload_lds16(Bg0, (char*)Bs[0] + lo0);
    gload_lds16(Bg1, (char*)Bs[0] + lo1);
    __syncthreads();

    for (int kt = 0; kt < K; kt += 32) {
        int cur = (kt >> 5) & 1;
        if (kt + 32 < K) {
            gload_lds16(Ag0 + kt + 32, (char*)As[cur ^ 1] + lo0);
            gload_lds16(Ag1 + kt + 32, (char*)As[cur ^ 1] + lo1);
            gload_lds16(Bg0 + kt + 32, (char*)Bs[cur ^ 1] + lo0);
            gload_lds16(Bg1 + kt + 32, (char*)Bs[cur ^ 1] + lo1);
        }

        half8 af[4], bf[4];
#pragma unroll
        for (int i = 0; i < 4; i++)
            af[i] = *(half8*)&As[cur][(wrow + i * 16 + l15) * 32 + quad * 8];
#pragma unroll
        for (int j = 0; j < 4; j++)
            bf[j] = *(half8*)&Bs[cur][(wcol + j * 16 + l15) * 32 + quad * 8];
#pragma unroll
        for (int i = 0; i < 4; i++)
#pragma unroll
            for (int j = 0; j < 4; j++)
                acc[i][j] = mfma16(af[i], bf[j], acc[i][j]);

        __syncthreads();
    }

#pragma unroll
    for (int j = 0; j < 4; j++) {
        float bv_ = bias[n0 + wcol + j * 16 + l15];
#pragma unroll
        for (int i = 0; i < 4; i++)
#pragma unroll
            for (int r = 0; r < 4; r++) acc[i][j][r] += bv_;
    }

    if (which < 2) {
        _Float16* C = which == 0 ? Qp : Kp;
#pragma unroll
        for (int i = 0; i < 4; i++) {
#pragma unroll
            for (int r = 0; r < 4; r++) {
                float s = 0.f;
#pragma unroll
                for (int j = 0; j < 4; j++) s += acc[i][j][r] * acc[i][j][r];
                s += __shfl_xor(s, 1);
                s += __shfl_xor(s, 2);
                s += __shfl_xor(s, 4);
                s += __shfl_xor(s, 8);
                float inv = 1.0f / fmaxf(sqrtf(s), 1e-12f);
                int row = m0 + wrow + i * 16 + quad * 4 + r;
#pragma unroll
                for (int j = 0; j < 4; j++) {
                    int col = n0 + wcol + j * 16 + l15;
                    C[(size_t)row * DD + col] = (_Float16)(acc[i][j][r] * inv);
                }
            }
        }
    } else {
#pragma unroll
        for (int j = 0; j < 4; j++) {
            int col = n0 + wcol + j * 16 + l15;  // h*64+dh
#pragma unroll
            for (int i = 0; i < 4; i++) {
#pragma unroll
                for (int r = 0; r < 4; r++) {
                    int row = m0 + wrow + i * 16 + quad * 4 + r;  // b*2048 + l
                    int b = row >> 11, l = row & 2047;
                    VtG[((size_t)((b << 10) + col)) * LL + l] = (_Float16)acc[i][j][r];
                }
            }
        }
    }
}

// ---------------- output projection GEMM (2-phase double-buffered, fp32 out) ----------
__global__ __launch_bounds__(256) void gemm_out(const _Float16* __restrict__ A,
                                                const _Float16* __restrict__ W,
                                                const float* __restrict__ bias,
                                                float* __restrict__ C) {
    const int K = 1024, N = 1024;
    __shared__ _Float16 As[2][128 * 32];
    __shared__ _Float16 Bs[2][128 * 32];

    int tid = threadIdx.x;
    int wave = tid >> 6, lane = tid & 63;
    int quad = lane >> 4, l15 = lane & 15;
    int wrow = (wave >> 1) * 64, wcol = (wave & 1) * 64;
    int m0 = blockIdx.y * 128;
    int n0 = blockIdx.x * 128;

    floatx4 acc[4][4] = {};

    int srow = tid >> 2, sseg = tid & 3;
    const _Float16* Ag0 = A + (size_t)(m0 + srow) * K + sseg * 8;
    const _Float16* Ag1 = Ag0 + (size_t)64 * K;
    const _Float16* Bg0 = W + (size_t)(n0 + srow) * K + sseg * 8;
    const _Float16* Bg1 = Bg0 + (size_t)64 * K;
    int lo0 = tid * 16, lo1 = (256 + tid) * 16;

    gload_lds16(Ag0, (char*)As[0] + lo0);
    gload_lds16(Ag1, (char*)As[0] + lo1);
    gload_lds16(Bg0, (char*)Bs[0] + lo0);
    gload_lds16(Bg1, (char*)Bs[0] + lo1);
    __syncthreads();

    for (int kt = 0; kt < K; kt += 32) {
        int cur = (kt >> 5) & 1;
        if (kt + 32 < K) {
            gload_lds16(Ag0 + kt + 32, (char*)As[cur ^ 1] + lo0);
            gload_lds16(Ag1 + kt + 32, (char*)As[cur ^ 1] + lo1);
            gload_lds16(Bg0 + kt + 32, (char*)Bs[cur ^ 1] + lo0);
            gload_lds16(Bg1 + kt + 32, (char*)Bs[cur ^ 1] + lo1);
        }

        half8 af[4], bf[4];
#pragma unroll
        for (int i = 0; i < 4; i++)
            af[i] = *(half8*)&As[cur][(wrow + i * 16 + l15) * 32 + quad * 8];
#pragma unroll
        for (int j = 0; j < 4; j++)
            bf[j] = *(half8*)&Bs[cur][(wcol + j * 16 + l15) * 32 + quad * 8];
#pragma unroll
        for (int i = 0; i < 4; i++)
#pragma unroll
            for (int j = 0; j < 4; j++)
                acc[i][j] = mfma16(af[i], bf[j], acc[i][j]);

        __syncthreads();
    }

#pragma unroll
    for (int j = 0; j < 4; j++) {
        int col = n0 + wcol + j * 16 + l15;
        float bv = bias[col];
#pragma unroll
        for (int i = 0; i < 4; i++) {
#pragma unroll
            for (int r = 0; r < 4; r++) {
                int row = m0 + wrow + i * 16 + quad * 4 + r;
                C[(size_t)row * N + col] = acc[i][j][r] + bv;
            }
        }
    }
}

// ---------------- fused cosine attention: k-split, barrier-free main loop ----------------
// grid (32, 64) = 2048 blocks, XCD-chunk swizzled. Block = 64 q-rows; 4 waves each own a
// PRIVATE 512-k range with private K/V LDS double-buffers (KVBLK=32). No __syncthreads in
// the loop: per tile each wave issues its next-tile global_load_lds prefetch, then a
// COUNTED s_waitcnt vmcnt(8) (prefetch stays in flight), computes 2 q-groups sharing
// kf/vf fragments. Epilogue: LDS combine of 4 partial (O, l) + wave-0 normalize/store.
__global__ __launch_bounds__(256) void attn_k(const _Float16* __restrict__ Q,
                                              const _Float16* __restrict__ K,
                                              const _Float16* __restrict__ VtG,
                                              _Float16* __restrict__ Mg) {
    // [0,32768): K stages [wave][buf][2048h]  (4KB per buf)
    // [32768,65536): V stages [wave][buf][2048h]
    // [65536,66560): lsumP[4][2][32] floats
    // combine overlay: bytes [0,49152) after loop (guarded by __syncthreads)
    __shared__ __attribute__((aligned(16))) char LDSBUF[66560];

    const float C2 = 20.60992915555662f;  // log2(e)/0.07
    const float OFF = 6.0f;

    int tid = threadIdx.x, wave = tid >> 6, lane = tid & 63;
    int l31 = lane & 31, hi = lane >> 5;

    // bijective XCD-chunked swizzle (2048 blocks = 8 XCDs x 256)
    int hw = blockIdx.x + blockIdx.y * gridDim.x;
    int logical = (hw & 7) * 256 + (hw >> 3);
    int bh = logical >> 5;            // 0..63
    int q0 = (logical & 31) * 64;     // 0..1984

    int b = bh >> 4, h = bh & 15;
    size_t rowBase = (size_t)b * LL;
    int colBase = h * 64;
    int k0 = wave * 512;              // wave-private k range
    int xorv = l31 & 7;

    // ---- Q fragments for both q-groups (row = q, dh = d*16 + hi*8 + j)
    half8 qfA[4], qfB[4];
    {
        const _Float16* qpA = Q + (rowBase + q0 + l31) * DD + colBase + hi * 8;
        const _Float16* qpB = qpA + (size_t)32 * DD;
#pragma unroll
        for (int d = 0; d < 4; d++) {
            qfA[d] = *(const half8*)(qpA + d * 16);
            qfB[d] = *(const half8*)(qpB + d * 16);
        }
    }

    // ---- staging pointers (linear LDS dest, pre-swizzled global source)
    // K subtile: 32 k-rows x 64 dh (rows of 128B, 8 chunks, chunk ^= row&7)
    // V subtile: 64 dh-rows x 32 k (rows of 64B, 4 chunks, chunk ^= row&3)
    const _Float16* kg[4];
    const _Float16* vg[4];
#pragma unroll
    for (int p = 0; p < 4; p++) {
        int s = p * 64 + lane;                 // 0..255
        int kr = s >> 3, kseg = (s & 7) ^ (kr & 7);
        kg[p] = K + (rowBase + k0 + kr) * DD + colBase + kseg * 8;
        int vr = s >> 2, vseg = (s & 3) ^ (vr & 3);
        vg[p] = VtG + ((size_t)bh * 64 + vr) * LL + k0 + vseg * 8;
    }
    char* kl = LDSBUF + wave * 8192;           // + buf*4096
    char* vl = LDSBUF + 32768 + wave * 8192;

    floatx16 oaccA[2] = {}, oaccB[2] = {};
    float fsA = 0.f, fsB = 0.f;

    // prologue: stage tile 0 into buf 0 (no wait here; loop's vmcnt(8) covers it)
#pragma unroll
    for (int p = 0; p < 4; p++) {
        gload_lds16(kg[p], kl + p * 1024 + lane * 16);
        gload_lds16(vg[p], vl + p * 1024 + lane * 16);
        kg[p] += (size_t)32 * DD;   // next 32 k-rows
        vg[p] += 32;                // next 32 k-cols
    }

#pragma unroll 2
    for (int t = 0; t < 16; t++) {
        int cur = t & 1;
        if (t < 15) {
            char* kld = kl + (cur ^ 1) * 4096;
            char* vld = vl + (cur ^ 1) * 4096;
#pragma unroll
            for (int p = 0; p < 4; p++) {
                gload_lds16(kg[p], kld + p * 1024 + lane * 16);
                gload_lds16(vg[p], vld + p * 1024 + lane * 16);
                kg[p] += (size_t)32 * DD;
                vg[p] += 32;
            }
            // counted wait: the 8 just-issued prefetch loads stay in flight;
            // everything older (current tile's stage) is drained.
            asm volatile("s_waitcnt vmcnt(8)" ::: "memory");
        } else {
            asm volatile("s_waitcnt vmcnt(0)" ::: "memory");
        }
        __builtin_amdgcn_sched_barrier(0);

        const char* kb = kl + cur * 4096;
        const char* vb = vl + cur * 4096;

        // ---- kf reads + QK^T for both q-groups (2 independent chains)
        half8 kf[4];
#pragma unroll
        for (int d = 0; d < 4; d++)
            kf[d] = *(const half8*)(kb + l31 * 128 + (((d * 2 + hi) ^ xorv) * 16));
        floatx16 stA = {}, stB = {};
        __builtin_amdgcn_s_setprio(1);
#pragma unroll
        for (int d = 0; d < 4; d++) {
            stA = mfma32(kf[d], qfA[d], stA);
            stB = mfma32(kf[d], qfB[d], stB);
        }
        __builtin_amdgcn_s_setprio(0);

        // ---- vf reads (shared by both q-groups)
        half8 vf[2][2];
#pragma unroll
        for (int jb = 0; jb < 2; jb++)
#pragma unroll
            for (int sl = 0; sl < 2; sl++)
                vf[jb][sl] = *(const half8*)(vb + (jb * 32 + l31) * 64 +
                                             (((sl * 2 + hi) ^ (l31 & 3)) * 16));

        // ---- softmax + pack, group A
        half8 pfA[2], pfB[2];
        {
            float e[16];
#pragma unroll
            for (int r = 0; r < 16; r++)
                e[r] = __builtin_amdgcn_exp2f(stA[r] * C2 - OFF);
            float s0 = (e[0] + e[1]) + (e[2] + e[3]);
            float s1 = (e[4] + e[5]) + (e[6] + e[7]);
            float s2 = (e[8] + e[9]) + (e[10] + e[11]);
            float s3 = (e[12] + e[13]) + (e[14] + e[15]);
            fsA += (s0 + s1) + (s2 + s3);
#pragma unroll
            for (int sl = 0; sl < 2; sl++) {
                int bse = sl * 8;
                unsigned a = pkh(e[bse + 0], e[bse + 1]);
                unsigned cc = pkh(e[bse + 2], e[bse + 3]);
                unsigned bb = pkh(e[bse + 4], e[bse + 5]);
                unsigned dd = pkh(e[bse + 6], e[bse + 7]);
                auto r1 = __builtin_amdgcn_permlane32_swap(a, bb, false, false);
                auto r2 = __builtin_amdgcn_permlane32_swap(cc, dd, false, false);
                uint4v u;
                u[0] = (unsigned)r1[0]; u[1] = (unsigned)r2[0];
                u[2] = (unsigned)r1[1]; u[3] = (unsigned)r2[1];
                pfA[sl] = __builtin_bit_cast(half8, u);
            }
        }
        // ---- softmax + pack, group B
        {
            float e[16];
#pragma unroll
            for (int r = 0; r < 16; r++)
                e[r] = __builtin_amdgcn_exp2f(stB[r] * C2 - OFF);
            float s0 = (e[0] + e[1]) + (e[2] + e[3]);
            float s1 = (e[4] + e[5]) + (e[6] + e[7]);
            float s2 = (e[8] + e[9]) + (e[10] + e[11]);
            float s3 = (e[12] + e[13]) + (e[14] + e[15]);
            fsB += (s0 + s1) + (s2 + s3);
#pragma unroll
            for (int sl = 0; sl < 2; sl++) {
                int bse = sl * 8;
                unsigned a = pkh(e[bse + 0], e[bse + 1]);
                unsigned cc = pkh(e[bse + 2], e[bse + 3]);
                unsigned bb = pkh(e[bse + 4], e[bse + 5]);
                unsigned dd = pkh(e[bse + 6], e[bse + 7]);
                auto r1 = __builtin_amdgcn_permlane32_swap(a, bb, false, false);
                auto r2 = __builtin_amdgcn_permlane32_swap(cc, dd, false, false);
                uint4v u;
                u[0] = (unsigned)r1[0]; u[1] = (unsigned)r2[0];
                u[2] = (unsigned)r1[1]; u[3] = (unsigned)r2[1];
                pfB[sl] = __builtin_bit_cast(half8, u);
            }
        }

        // ---- PV for both q-groups (vf reused from registers)
        __builtin_amdgcn_s_setprio(1);
#pragma unroll
        for (int jb = 0; jb < 2; jb++)
#pragma unroll
            for (int sl = 0; sl < 2; sl++) {
                oaccA[jb] = mfma32(pfA[sl], vf[jb][sl], oaccA[jb]);
                oaccB[jb] = mfma32(pfB[sl], vf[jb][sl], oaccB[jb]);
            }
        __builtin_amdgcn_s_setprio(0);
    }

    // ---- write per-wave row-sum partials
    fsA += __shfl_xor(fsA, 32);
    fsB += __shfl_xor(fsB, 32);
    float* lsumPf = (float*)(LDSBUF + 65536);   // [w][g][32]
    if (lane < 32) {
        lsumPf[wave * 64 + l31] = fsA;
        lsumPf[wave * 64 + 32 + l31] = fsB;
    }

    __syncthreads();   // all waves done with loop; stage LDS now dead

    // ---- combine: waves 1..3 write O partials into overlay [w-1][f][lane]
    if (wave != 0) {
        char* cb = LDSBUF + (wave - 1) * 16384;
#pragma unroll
        for (int jb = 0; jb < 2; jb++)
#pragma unroll
            for (int q4 = 0; q4 < 4; q4++) {
                floatx4 va, vb2;
#pragma unroll
                for (int r = 0; r < 4; r++) {
                    va[r] = oaccA[jb][q4 * 4 + r];
                    vb2[r] = oaccB[jb][q4 * 4 + r];
                }
                *(floatx4*)(cb + (jb * 4 + q4) * 1024 + lane * 16) = va;
                *(floatx4*)(cb + ((2 + jb) * 4 + q4) * 1024 + lane * 16) = vb2;
            }
    }
    __syncthreads();

    if (wave == 0) {
#pragma unroll
        for (int w1 = 0; w1 < 3; w1++) {
            char* cb = LDSBUF + w1 * 16384;
#pragma unroll
            for (int jb = 0; jb < 2; jb++)
#pragma unroll
                for (int q4 = 0; q4 < 4; q4++) {
                    floatx4 va = *(floatx4*)(cb + (jb * 4 + q4) * 1024 + lane * 16);
                    floatx4 vb2 = *(floatx4*)(cb + ((2 + jb) * 4 + q4) * 1024 + lane * 16);
#pragma unroll
                    for (int r = 0; r < 4; r++) {
                        oaccA[jb][q4 * 4 + r] += va[r];
                        oaccB[jb][q4 * 4 + r] += vb2[r];
                    }
                }
        }
        // combined row sums: lane (hi,l31) holds total for group hi, q=l31
        float tq = lsumPf[0 * 64 + hi * 32 + l31] + lsumPf[1 * 64 + hi * 32 + l31] +
                   lsumPf[2 * 64 + hi * 32 + l31] + lsumPf[3 * 64 + hi * 32 + l31];
        float invq = 1.0f / tq;

#pragma unroll
        for (int g = 0; g < 2; g++)
#pragma unroll
            for (int jb = 0; jb < 2; jb++)
#pragma unroll
                for (int r = 0; r < 16; r++) {
                    int crow = (r & 3) + 8 * (r >> 2) + 4 * hi;
                    float iv = __shfl(invq, g * 32 + crow);
                    float val = (g ? oaccB : oaccA)[jb][r] * iv;
                    Mg[(rowBase + q0 + g * 32 + crow) * DD + colBase + jb * 32 + l31] =
                        (_Float16)val;
                }
    }
}

// ---------------- launch ----------------
extern "C" void kernel_launch(void* const* d_in, const int* in_sizes, int n_in,
                              void* d_out, int out_size, void* d_ws, size_t ws_size,
                              hipStream_t stream) {
    (void)in_sizes; (void)n_in; (void)out_size; (void)ws_size;
    const float* q  = (const float*)d_in[0];
    const float* k  = (const float*)d_in[1];
    const float* v  = (const float*)d_in[2];
    const float* Wq = (const float*)d_in[3];
    const float* bq = (const float*)d_in[4];
    const float* Wk = (const float*)d_in[5];
    const float* bk = (const float*)d_in[6];
    const float* Wv = (const float*)d_in[7];
    const float* bv = (const float*)d_in[8];
    const float* Wo = (const float*)d_in[9];
    const float* bo = (const float*)d_in[10];

    const size_t NQKV = (size_t)MM * DD;  // 8388608
    const size_t NW = (size_t)DD * DD;    // 1048576

    _Float16* q16  = (_Float16*)d_ws;
    _Float16* k16  = q16 + NQKV;
    _Float16* v16  = k16 + NQKV;
    _Float16* wq16 = v16 + NQKV;
    _Float16* wk16 = wq16 + NW;
    _Float16* wv16 = wk16 + NW;
    _Float16* wo16 = wv16 + NW;
    _Float16* Qp   = wo16 + NW;
    _Float16* Kp   = Qp + NQKV;
    _Float16* VtG  = Kp + NQKV;
    _Float16* Mg   = VtG + NQKV;
    (void)k16; (void)v16;

    // one fused convert: 3*8192 + 4*1024 blocks
    cvt_all<<<dim3(3 * 8192 + 4 * 1024), dim3(256), 0, stream>>>(q, k, v, Wq, Wk, Wv, Wo, q16);

    // fused QKV projection (+l2norm on Q/K, transposed V); A = q16/k16/v16 by block
    gemm_qkv<<<dim3(24, MM / 128), dim3(256), 0, stream>>>(q16, wq16, wk16, wv16,
                                                           bq, bk, bv, Qp, Kp, VtG);

    // fused attention (k-split, barrier-free main loop)
    attn_k<<<dim3(32, 64), dim3(256), 0, stream>>>(Qp, Kp, VtG, Mg);

    // output projection -> fp32 d_out
    gemm_out<<<dim3(1024 / 128, MM / 128), dim3(256), 0, stream>>>(Mg, wo16, bo, (float*)d_out);
}